// Round 11
// baseline (542.679 us; speedup 1.0000x reference)
//
#include <hip/hip_runtime.h>

#define B_   2
#define S_   2048
#define D_   4096
#define H_   32
#define KVH_ 8
#define HD_  128
#define NE_  6144   // (KVH*2+H)*HD

using f32x4  = __attribute__((ext_vector_type(4))) float;
using bf16x8 = __attribute__((ext_vector_type(8))) __bf16;
using u16x8  = __attribute__((ext_vector_type(8))) unsigned short;

__device__ __forceinline__ unsigned short f2bf(float f) {
  union { float f; unsigned u; } v; v.f = f;
  unsigned r = v.u + 0x7FFFu + ((v.u >> 16) & 1u);
  return (unsigned short)(r >> 16);
}
__device__ __forceinline__ float bf2f(unsigned short h) {
  union { unsigned u; float f; } v; v.u = ((unsigned)h) << 16; return v.f;
}
__device__ __forceinline__ bf16x8 ld8(const unsigned short* p) {
  return *reinterpret_cast<const bf16x8*>(p);
}
__device__ __forceinline__ bf16x8 ld8b(const void* base, int byte_off) {
  return *reinterpret_cast<const bf16x8*>((const char*)base + byte_off);
}
__device__ __forceinline__ void cp16(const void* g, void* l) {
  __builtin_amdgcn_global_load_lds(
      (const __attribute__((address_space(1))) void*)g,
      (__attribute__((address_space(3))) void*)l, 16, 0, 0);
}
__device__ __forceinline__ float exp2a(float x) {   // 2^x via v_exp_f32
  float r; asm("v_exp_f32 %0, %1" : "=v"(r) : "v"(x)); return r;
}

// ---------------------------------------------------------------------------
// fp32 -> bf16 (RNE), 4 elems/thread. Single-segment.
// ---------------------------------------------------------------------------
__global__ __launch_bounds__(256) void cvt_f32_bf16(
    const float* __restrict__ in, unsigned short* __restrict__ out, int n4)
{
  int i = blockIdx.x * 256 + threadIdx.x;
  if (i >= n4) return;
  f32x4 v = *reinterpret_cast<const f32x4*>(in + (size_t)i * 4);
  ushort4 o;
  o.x = f2bf(v[0]); o.y = f2bf(v[1]); o.z = f2bf(v[2]); o.w = f2bf(v[3]);
  *reinterpret_cast<ushort4*>(out + (size_t)i * 4) = o;
}

// Two segments in one launch (dests must be disjoint!).
__global__ __launch_bounds__(256) void cvt2_f32_bf16(
    const float* __restrict__ s0, unsigned short* __restrict__ d0, int n0,
    const float* __restrict__ s1, unsigned short* __restrict__ d1, int n1)
{
  int i = blockIdx.x * 256 + threadIdx.x;
  const float* src; unsigned short* dst;
  if (i < n0) { src = s0; dst = d0; }
  else        { i -= n0; if (i >= n1) return; src = s1; dst = d1; }
  f32x4 v = *reinterpret_cast<const f32x4*>(src + (size_t)i * 4);
  ushort4 o;
  o.x = f2bf(v[0]); o.y = f2bf(v[1]); o.z = f2bf(v[2]); o.w = f2bf(v[3]);
  *reinterpret_cast<ushort4*>(dst + (size_t)i * 4) = o;
}

// ---------------------------------------------------------------------------
// 256xNT-tile 8-phase GEMM: C[M,N] = A[M,K] * B[N,K]^T, K=4096 fixed.
// (unchanged from round 10: GEMM1 1034 TF, 0 bank conflicts)
// ---------------------------------------------------------------------------
template <typename OutT, int NT>
__global__ __launch_bounds__(512, 2) void gemm256(
    const unsigned short* __restrict__ A,
    const unsigned short* __restrict__ Bw,
    OutT* __restrict__ C, int M, int N)
{
  constexpr int K  = 4096;
  constexpr int NI = (K / 64) / 2;     // 32 iterations, 2 K-tiles each
  constexpr int NB = NT / 64;          // B chunks per tile (3 or 4)
  constexpr int NN = NT / 64;          // n-frags per wave
  constexpr int WN = NT / 4;           // per-wave N extent
  constexpr int BBUF = NT * 128;       // B bytes per buffer
  __shared__ __align__(16) char lds[65536 + 2 * BBUF];

  const int tid  = threadIdx.x;
  const int lane = tid & 63;
  const int wave = tid >> 6;
  const int wr = wave >> 2;            // 0..1  (M half)
  const int wc = wave & 3;             // 0..3  (N quarter)
  const int lr = lane & 15;
  const int lk = (lane >> 4) * 8;

  int id  = blockIdx.y * gridDim.x + blockIdx.x;
  const int nwg = gridDim.x * gridDim.y;
  if ((nwg & 7) == 0) { const int q = nwg >> 3; id = (id & 7) * q + (id >> 3); }
  const int row0 = (id / gridDim.x) * 256;
  const int col0 = (id % gridDim.x) * NT;

  // A staging: 2 halves x 2 loads/thread (16KB each).
  int rwA[2], csA[2], dbA[2];
#pragma unroll
  for (int j = 0; j < 2; ++j) {
    dbA[j] = j * 8192 + tid * 16;
    rwA[j] = dbA[j] >> 7;
    csA[j] = ((dbA[j] & 127) ^ ((rwA[j] & 7) << 4)) >> 1;
  }
  auto stA = [&](int buf, int h, int t) {
#pragma unroll
    for (int j = 0; j < 2; ++j)
      cp16(A + (size_t)(row0 + h * 128 + rwA[j]) * K + t * 64 + csA[j],
           lds + buf * 32768 + h * 16384 + dbA[j]);
  };
  // B staging: NB chunks x 1 load/thread (8KB each, 64 rows).
  const int dbB = tid * 16;
  const int rwB = dbB >> 7;                              // 0..63
  const int csB = ((dbB & 127) ^ ((rwB & 7) << 4)) >> 1; // chunk row base %8==0
  auto stB = [&](int buf, int c, int t) {
    cp16(Bw + (size_t)(col0 + c * 64 + rwB) * K + t * 64 + csB,
         lds + 65536 + buf * BBUF + c * 8192 + dbB);
  };

  const int cb0 = ((0 + lk) << 1) ^ ((lr & 7) << 4);
  const int cb1 = ((32 + lk) << 1) ^ ((lr & 7) << 4);
  const int aRowB = (wr * 128 + lr) * 128;
  const int bRowB = (wc * WN + lr) * 128;

  f32x4 acc[8][NN];
#pragma unroll
  for (int m = 0; m < 8; ++m)
#pragma unroll
    for (int n = 0; n < NN; ++n) acc[m][n] = (f32x4){0.f, 0.f, 0.f, 0.f};
  bf16x8 bfr[NN][2];

#define FENCE asm volatile("" ::: "memory")
#define VMNB  do { if constexpr (NB == 4) asm volatile("s_waitcnt vmcnt(4)" ::: "memory"); \
                   else                   asm volatile("s_waitcnt vmcnt(3)" ::: "memory"); } while (0)
#define VM0   asm volatile("s_waitcnt vmcnt(0)" ::: "memory")

#define PHASE(p, buf, STAGE, WAIT)                                             \
  {                                                                            \
    if ((p) == 0) {                                                            \
      _Pragma("unroll")                                                        \
      for (int n = 0; n < NN; ++n) {                                           \
        bfr[n][0] = ld8b(lds, 65536 + (buf) * BBUF + bRowB + n * 2048 + cb0);  \
        bfr[n][1] = ld8b(lds, 65536 + (buf) * BBUF + bRowB + n * 2048 + cb1);  \
      }                                                                        \
    }                                                                          \
    bf16x8 a00 = ld8b(lds, (buf) * 32768 + aRowB + ((p) * 2 + 0) * 2048 + cb0);\
    bf16x8 a01 = ld8b(lds, (buf) * 32768 + aRowB + ((p) * 2 + 0) * 2048 + cb1);\
    bf16x8 a10 = ld8b(lds, (buf) * 32768 + aRowB + ((p) * 2 + 1) * 2048 + cb0);\
    bf16x8 a11 = ld8b(lds, (buf) * 32768 + aRowB + ((p) * 2 + 1) * 2048 + cb1);\
    STAGE;                                                                     \
    FENCE;                                                                     \
    __builtin_amdgcn_s_barrier();                                              \
    __builtin_amdgcn_s_setprio(1);                                             \
    _Pragma("unroll")                                                          \
    for (int n = 0; n < NN; ++n) {                                             \
      acc[(p)*2+0][n] = __builtin_amdgcn_mfma_f32_16x16x32_bf16(a00, bfr[n][0], acc[(p)*2+0][n], 0, 0, 0); \
      acc[(p)*2+0][n] = __builtin_amdgcn_mfma_f32_16x16x32_bf16(a01, bfr[n][1], acc[(p)*2+0][n], 0, 0, 0); \
      acc[(p)*2+1][n] = __builtin_amdgcn_mfma_f32_16x16x32_bf16(a10, bfr[n][0], acc[(p)*2+1][n], 0, 0, 0); \
      acc[(p)*2+1][n] = __builtin_amdgcn_mfma_f32_16x16x32_bf16(a11, bfr[n][1], acc[(p)*2+1][n], 0, 0, 0); \
    }                                                                          \
    __builtin_amdgcn_s_setprio(0);                                             \
    WAIT;                                                                      \
    FENCE;                                                                     \
    __builtin_amdgcn_s_barrier();                                              \
  }

  // Prologue: tile0 B+A into buf0, tile1 B into buf1; allow tile1-B in flight.
#pragma unroll
  for (int c = 0; c < NB; ++c) stB(0, c, 0);
  stA(0, 0, 0); stA(0, 1, 0);
#pragma unroll
  for (int c = 0; c < NB; ++c) stB(1, c, 1);
  VMNB;
  FENCE;
  __builtin_amdgcn_s_barrier();

  for (int i = 0; i < NI; ++i) {
    const int t1  = 2 * i + 1;
    const int tn0 = 2 * i + 2;
    const int tn1 = 2 * i + 3;
    const bool pre = (i + 1 < NI);
    // K-tile 2i in buf0
    PHASE(0, 0, { stA(1, 0, t1); }, {});
    PHASE(1, 0, { stA(1, 1, t1); }, {});
    PHASE(2, 0, { if (pre) { stB(0, 0, tn0); stB(0, 1, tn0); } }, {});
    PHASE(3, 0, { if (pre) { _Pragma("unroll") for (int c = 2; c < NB; ++c) stB(0, c, tn0); } },
          { if (pre) { VMNB; } else { VM0; } });
    // K-tile 2i+1 in buf1
    PHASE(0, 1, { if (pre) stA(0, 0, tn0); }, {});
    PHASE(1, 1, { if (pre) stA(0, 1, tn0); }, {});
    PHASE(2, 1, { if (pre) { stB(1, 0, tn1); stB(1, 1, tn1); } }, {});
    PHASE(3, 1, { if (pre) { _Pragma("unroll") for (int c = 2; c < NB; ++c) stB(1, c, tn1); } },
          { if (pre) { VMNB; } });
  }
#undef PHASE
#undef FENCE
#undef VMNB
#undef VM0

  const int orow = (lane >> 4) * 4;
#pragma unroll
  for (int m = 0; m < 8; ++m) {
    const int gr0 = row0 + wr * 128 + m * 16 + orow;
#pragma unroll
    for (int n = 0; n < NN; ++n) {
      const int gc = col0 + wc * WN + n * 16 + lr;
#pragma unroll
      for (int r = 0; r < 4; ++r) {
        float val = acc[m][n][r];
        if constexpr (sizeof(OutT) == 2)
          C[(size_t)(gr0 + r) * N + gc] = f2bf(val);
        else
          C[(size_t)(gr0 + r) * N + gc] = val;
      }
    }
  }
}

// ---------------------------------------------------------------------------
// Split fused[B,S,48,128] into Qr (rope), Kr (rope), Vt (transposed).
// Vectorized (G13): thread handles 8 consecutive d in [0,64) -> 16B loads,
// 16B Q/K stores. V stays scalar (transposed stores are inherently strided).
// ---------------------------------------------------------------------------
__global__ __launch_bounds__(256) void rope_scatter(
    const unsigned short* __restrict__ fused,
    unsigned short* __restrict__ Qr,
    unsigned short* __restrict__ Kr,
    unsigned short* __restrict__ Vt)
{
  int idx = blockIdx.x * 256 + threadIdx.x;  // [0, B*S*48*8)
  int dg = idx & 7;            // d = dg*8 + jj
  int t = idx >> 3;
  int e = t % 48;
  int bs = t / 48;
  int s = bs % S_;
  int b = bs / S_;
  int kvh = e / 6, j = e % 6;
  const unsigned short* src = fused + (size_t)bs * NE_ + e * 128 + dg * 8;
  u16x8 lo = *reinterpret_cast<const u16x8*>(src);
  u16x8 hi = *reinterpret_cast<const u16x8*>(src + 64);
  if (j == 5) {  // V: transposed store
    size_t base = (size_t)(b * KVH_ + kvh) * HD_ * S_ + s;
#pragma unroll
    for (int jj = 0; jj < 8; ++jj) {
      Vt[base + (size_t)(dg * 8 + jj) * S_]      = lo[jj];
      Vt[base + (size_t)(dg * 8 + jj + 64) * S_] = hi[jj];
    }
  } else {
    u16x8 olo, ohi;
#pragma unroll
    for (int jj = 0; jj < 8; ++jj) {
      int d = dg * 8 + jj;
      float x1 = bf2f(lo[jj]), x2 = bf2f(hi[jj]);
      float inv = __expf(-(float)d * (9.2103403719761836f / 64.0f));
      float ang = (float)s * inv;
      float sn, c;
      sincosf(ang, &sn, &c);
      olo[jj] = f2bf(x1 * c - x2 * sn);
      ohi[jj] = f2bf(x2 * c + x1 * sn);
    }
    unsigned short* dst;
    if (j == 4) dst = Kr + ((size_t)(b * KVH_ + kvh) * S_ + s) * HD_;
    else        dst = Qr + ((size_t)(b * H_ + kvh * 4 + j) * S_ + s) * HD_;
    *reinterpret_cast<u16x8*>(dst + dg * 8)      = olo;
    *reinterpret_cast<u16x8*>(dst + dg * 8 + 64) = ohi;
  }
}

// ---------------------------------------------------------------------------
// Causal GQA flash attention, QBLK=128: 4 waves x 32 q-rows (2 m-frags).
// Each kf/vf ds_read now feeds TWO MFMAs -> LDS-read per MFMA halved
// (was the binding constraint: 34 reads/32 MFMA -> 36/64).
// K/V double-buffered + prefetch-first; log2-domain softmax, per-lane
// partials, defer-max (round 10). LDS 80 KB -> 2 blocks/CU; grid 512 = 2/CU.
// ---------------------------------------------------------------------------
__global__ __launch_bounds__(256) void attn_fwd(
    const unsigned short* __restrict__ Qr,
    const unsigned short* __restrict__ Kr,
    const unsigned short* __restrict__ Vt,
    unsigned short* __restrict__ O)
{
  __shared__ __align__(16) unsigned short Kld[2][64 * 128];
  __shared__ __align__(16) unsigned short Vld[2][128 * 64];
  __shared__ __align__(16) unsigned short Pld[4][32 * 64];

  const int tid  = threadIdx.x;
  const int lane = tid & 63;
  const int wave = tid >> 6;
  const int bx = blockIdx.x;   // 0..7
  const int h  = blockIdx.y;   // 0..31
  const int b  = blockIdx.z;   // 0..1
  const int kvh = h >> 2;
  const int lr = lane & 15;
  const int lk = (lane >> 4) * 8;
  const int orow = (lane >> 4) * 4;

  const float SC2 = 0.08838834764831845f * 1.4426950408889634f; // scale*log2e
  const unsigned short* Kb = Kr + (size_t)(b * KVH_ + kvh) * S_ * HD_;
  const unsigned short* Vb = Vt + (size_t)(b * KVH_ + kvh) * HD_ * S_;

  auto stage = [&](int buf, int kb) {
#pragma unroll
    for (int i = 0; i < 4; ++i) {
      const int db = i * 4096 + tid * 16;
      {  // K: 256 B/row
        const int row  = db >> 8;
        const int colb = (db & 255) ^ ((row & 7) << 4);
        cp16(Kb + (size_t)(kb * 64 + row) * HD_ + (colb >> 1),
             (char*)&Kld[buf][0] + i * 4096 + wave * 1024);
      }
      {  // V: 128 B/row
        const int row  = db >> 7;
        const int colb = (db & 127) ^ ((row & 7) << 4);
        cp16(Vb + (size_t)row * S_ + kb * 64 + (colb >> 1),
             (char*)&Vld[buf][0] + i * 4096 + wave * 1024);
      }
    }
  };

  for (int half = 0; half < 2; ++half) {
    const int qt = half ? (15 - bx) : bx;   // 128-row q-tile, 0..15
    const int nkb = 2 * (qt + 1);           // 64-row KV tiles (causal)

    bf16x8 qf[2][4];
#pragma unroll
    for (int fr = 0; fr < 2; ++fr) {
      const unsigned short* qbase =
          Qr + ((size_t)(b * H_ + h) * S_ + qt * 128 + wave * 32 + fr * 16 + lr) * HD_;
#pragma unroll
      for (int t = 0; t < 4; ++t) {
        union { bf16x8 v; unsigned short s2[8]; } u;
        u.v = ld8(qbase + t * 32 + lk);
#pragma unroll
        for (int jj = 0; jj < 8; ++jj) u.s2[jj] = f2bf(bf2f(u.s2[jj]) * SC2);
        qf[fr][t] = u.v;
      }
    }

    f32x4 acc_o[2][8];
#pragma unroll
    for (int fr = 0; fr < 2; ++fr)
#pragma unroll
      for (int dt = 0; dt < 8; ++dt) acc_o[fr][dt] = (f32x4){0.f, 0.f, 0.f, 0.f};
    float mrow[2][4], lpart[2][4];
#pragma unroll
    for (int fr = 0; fr < 2; ++fr)
#pragma unroll
      for (int r = 0; r < 4; ++r) { mrow[fr][r] = -1e30f; lpart[fr][r] = 0.f; }

    stage(0, 0);
    __syncthreads();

    for (int kb = 0; kb < nkb; ++kb) {
      const int cur = kb & 1;
      if (kb + 1 < nkb) stage(cur ^ 1, kb + 1);   // prefetch next tile FIRST

      const char* Kc = (const char*)&Kld[cur][0];
      const char* Vc = (const char*)&Vld[cur][0];

      // S = Q K^T: each kf read feeds BOTH m-frags
      f32x4 accs[2][4];
#pragma unroll
      for (int fr = 0; fr < 2; ++fr)
#pragma unroll
        for (int kt = 0; kt < 4; ++kt) accs[fr][kt] = (f32x4){0.f, 0.f, 0.f, 0.f};
      __builtin_amdgcn_s_setprio(1);
#pragma unroll
      for (int t = 0; t < 4; ++t) {
#pragma unroll
        for (int kt = 0; kt < 4; ++kt) {
          const int krow = kt * 16 + lr;
          const int kbyte = ((krow << 8) + ((t * 32 + lk) << 1)) ^ ((krow & 7) << 4);
          bf16x8 kf = ld8b(Kc, kbyte);
          accs[0][kt] = __builtin_amdgcn_mfma_f32_16x16x32_bf16(qf[0][t], kf, accs[0][kt], 0, 0, 0);
          accs[1][kt] = __builtin_amdgcn_mfma_f32_16x16x32_bf16(qf[1][t], kf, accs[1][kt], 0, 0, 0);
        }
      }
      __builtin_amdgcn_s_setprio(0);

      if (kb >= 2 * qt) {  // diagonal region: last two KV tiles
        const int koff = (kb - 2 * qt) * 64;
#pragma unroll
        for (int fr = 0; fr < 2; ++fr)
#pragma unroll
          for (int r = 0; r < 4; ++r) {
            const int qg = wave * 32 + fr * 16 + orow + r;
#pragma unroll
            for (int kt = 0; kt < 4; ++kt)
              if (koff + kt * 16 + lr > qg) accs[fr][kt][r] = -1e30f;
          }
      }

      // in-lane kt-max; defer-check without cross-lane reduce
      float mx[2][4];
#pragma unroll
      for (int fr = 0; fr < 2; ++fr)
#pragma unroll
        for (int r = 0; r < 4; ++r)
          mx[fr][r] = fmaxf(fmaxf(accs[fr][0][r], accs[fr][1][r]),
                            fmaxf(accs[fr][2][r], accs[fr][3][r]));
      int ok = 1;
#pragma unroll
      for (int fr = 0; fr < 2; ++fr)
#pragma unroll
        for (int r = 0; r < 4; ++r) ok &= (mx[fr][r] <= mrow[fr][r] + 8.f);
      if (!__all(ok)) {   // rare: running max grew; full rescale
#pragma unroll
        for (int fr = 0; fr < 2; ++fr) {
          float corr[4];
#pragma unroll
          for (int r = 0; r < 4; ++r) {
            float m = mx[fr][r];
#pragma unroll
            for (int msk = 8; msk >= 1; msk >>= 1) m = fmaxf(m, __shfl_xor(m, msk, 64));
            float mnew = fmaxf(mrow[fr][r], m);
            corr[r] = exp2a(mrow[fr][r] - mnew);
            mrow[fr][r] = mnew;
            lpart[fr][r] *= corr[r];
          }
#pragma unroll
          for (int dt = 0; dt < 8; ++dt)
#pragma unroll
            for (int r = 0; r < 4; ++r) acc_o[fr][dt][r] *= corr[r];
        }
      }

      // p = exp2(s - m); per-lane partials; bf16 P store (swizzled)
#pragma unroll
      for (int fr = 0; fr < 2; ++fr)
#pragma unroll
        for (int r = 0; r < 4; ++r) {
          const int prow = fr * 16 + orow + r;
#pragma unroll
          for (int kt = 0; kt < 4; ++kt) {
            float p = exp2a(accs[fr][kt][r] - mrow[fr][r]);
            lpart[fr][r] += p;
            const int pbyte = ((prow << 7) + ((kt * 16 + lr) << 1)) ^ ((prow & 7) << 4);
            *(__bf16*)((char*)&Pld[wave][0] + pbyte) = (__bf16)p;
          }
        }

      asm volatile("" ::: "memory");  // Pld ushort-write vs bf16x8-read (TBAA)

      // O += P V: each vf read feeds BOTH m-frags
      __builtin_amdgcn_s_setprio(1);
#pragma unroll
      for (int kc = 0; kc < 2; ++kc) {
        bf16x8 pf[2];
#pragma unroll
        for (int fr = 0; fr < 2; ++fr) {
          const int pr = fr * 16 + lr;
          pf[fr] = ld8b(&Pld[wave][0],
                        ((pr << 7) + ((kc * 32 + lk) << 1)) ^ ((pr & 7) << 4));
        }
#pragma unroll
        for (int dt = 0; dt < 8; ++dt) {
          const int vrow = dt * 16 + lr;
          const int vbyte = ((vrow << 7) + ((kc * 32 + lk) << 1)) ^ ((vrow & 7) << 4);
          bf16x8 vf = ld8b(Vc, vbyte);
          acc_o[0][dt] = __builtin_amdgcn_mfma_f32_16x16x32_bf16(pf[0], vf, acc_o[0][dt], 0, 0, 0);
          acc_o[1][dt] = __builtin_amdgcn_mfma_f32_16x16x32_bf16(pf[1], vf, acc_o[1][dt], 0, 0, 0);
        }
      }
      __builtin_amdgcn_s_setprio(0);

      __syncthreads();  // lands prefetch + separates buffer reuse
    }

    // one cross-lane sum reduce per row at the end
#pragma unroll
    for (int fr = 0; fr < 2; ++fr)
#pragma unroll
      for (int r = 0; r < 4; ++r) {
        float s = lpart[fr][r];
#pragma unroll
        for (int msk = 8; msk >= 1; msk >>= 1) s += __shfl_xor(s, msk, 64);
        float inv = 1.f / s;
        size_t rowoff =
            (size_t)(b * S_ + qt * 128 + wave * 32 + fr * 16 + orow + r) * (H_ * HD_) + h * HD_;
#pragma unroll
        for (int dt = 0; dt < 8; ++dt)
          O[rowoff + dt * 16 + lr] = f2bf(acc_o[fr][dt][r] * inv);
      }
  }
}

// Diagnostic: if ws_size is too small, fill fp32 output with sentinel 12345.
__global__ void fill_sentinel(float* __restrict__ O, int n) {
  int i = blockIdx.x * 256 + threadIdx.x;
  if (i < n) O[i] = 12345.0f;
}

// ---------------------------------------------------------------------------
extern "C" void kernel_launch(void* const* d_in, const int* in_sizes, int n_in,
                              void* d_out, int out_size, void* d_ws, size_t ws_size,
                              hipStream_t stream) {
  const float* hidden = (const float*)d_in[0]; // [B,S,D] fp32
  const float* wqkv   = (const float*)d_in[1]; // [6144,4096] fp32
  const float* wdense = (const float*)d_in[2]; // [4096,4096] fp32
  float* out = (float*)d_out;                  // [B,S,4096] fp32

  const size_t NEED = 134217728;
  if (ws_size < NEED) {
    fill_sentinel<<<dim3((out_size + 255) / 256), dim3(256), 0, stream>>>(out, out_size);
    return;
  }

  char* ws = (char*)d_ws;
  // Phase 1 layout
  unsigned short* Hb    = (unsigned short*)(ws);                 // 33,554,432 B
  unsigned short* Wqb   = (unsigned short*)(ws + 33554432);      // 50,331,648 B
  unsigned short* fused = (unsigned short*)(ws + 83886080);      // 50,331,648 B
  // Phase 2 layout (after GEMM1: Hb/Wqb dead; Wdb sequenced AFTER GEMM1!)
  unsigned short* Qr    = (unsigned short*)(ws);                 // 33,554,432 B
  unsigned short* Kr    = (unsigned short*)(ws + 33554432);      //  8,388,608 B
  unsigned short* Vt    = (unsigned short*)(ws + 41943040);      //  8,388,608 B
  unsigned short* Wdb   = (unsigned short*)(ws + 50331648);      // 33,554,432 B
  unsigned short* attn_out = (unsigned short*)(ws + 83886080);   // 33,554,432 B (over fused)

  const int nH4 = B_ * S_ * D_ / 4;   // 4,194,304
  const int nQ4 = NE_ * D_ / 4;       // 6,291,456
  const int nD4 = D_ * D_ / 4;        // 4,194,304

  cvt2_f32_bf16<<<dim3((nH4 + nQ4 + 255) / 256), dim3(256), 0, stream>>>(
      hidden, Hb, nH4, wqkv, Wqb, nQ4);

  gemm256<unsigned short, 192><<<dim3(NE_ / 192, (B_ * S_) / 256), dim3(512), 0, stream>>>(
      Hb, Wqb, fused, B_ * S_, NE_);

  cvt_f32_bf16<<<dim3(nD4 / 256), dim3(256), 0, stream>>>(wdense, Wdb, nD4);

  rope_scatter<<<dim3((B_ * S_ * 48 * 8) / 256), dim3(256), 0, stream>>>(
      fused, Qr, Kr, Vt);

  attn_fwd<<<dim3(8, H_, B_), dim3(256), 0, stream>>>(Qr, Kr, Vt, attn_out);

  gemm256<float, 256><<<dim3(D_ / 256, (B_ * S_) / 256), dim3(512), 0, stream>>>(
      attn_out, Wdb, out, B_ * S_, D_);
}

// Round 12
// 528.789 us; speedup vs baseline: 1.0263x; 1.0263x over previous
//
#include <hip/hip_runtime.h>

#define B_   2
#define S_   2048
#define D_   4096
#define H_   32
#define KVH_ 8
#define HD_  128
#define NE_  6144   // (KVH*2+H)*HD

using f32x4  = __attribute__((ext_vector_type(4))) float;
using bf16x8 = __attribute__((ext_vector_type(8))) __bf16;
using u16x8  = __attribute__((ext_vector_type(8))) unsigned short;

__device__ __forceinline__ unsigned short f2bf(float f) {
  union { float f; unsigned u; } v; v.f = f;
  unsigned r = v.u + 0x7FFFu + ((v.u >> 16) & 1u);
  return (unsigned short)(r >> 16);
}
__device__ __forceinline__ float bf2f(unsigned short h) {
  union { unsigned u; float f; } v; v.u = ((unsigned)h) << 16; return v.f;
}
__device__ __forceinline__ bf16x8 ld8(const unsigned short* p) {
  return *reinterpret_cast<const bf16x8*>(p);
}
__device__ __forceinline__ bf16x8 ld8b(const void* base, int byte_off) {
  return *reinterpret_cast<const bf16x8*>((const char*)base + byte_off);
}
__device__ __forceinline__ void cp16(const void* g, void* l) {
  __builtin_amdgcn_global_load_lds(
      (const __attribute__((address_space(1))) void*)g,
      (__attribute__((address_space(3))) void*)l, 16, 0, 0);
}
__device__ __forceinline__ float exp2a(float x) {   // 2^x via v_exp_f32
  float r; asm("v_exp_f32 %0, %1" : "=v"(r) : "v"(x)); return r;
}

// ---------------------------------------------------------------------------
// fp32 -> bf16 (RNE), 4 elems/thread. Single-segment.
// ---------------------------------------------------------------------------
__global__ __launch_bounds__(256) void cvt_f32_bf16(
    const float* __restrict__ in, unsigned short* __restrict__ out, int n4)
{
  int i = blockIdx.x * 256 + threadIdx.x;
  if (i >= n4) return;
  f32x4 v = *reinterpret_cast<const f32x4*>(in + (size_t)i * 4);
  ushort4 o;
  o.x = f2bf(v[0]); o.y = f2bf(v[1]); o.z = f2bf(v[2]); o.w = f2bf(v[3]);
  *reinterpret_cast<ushort4*>(out + (size_t)i * 4) = o;
}

// Two segments in one launch (dests must be disjoint!).
__global__ __launch_bounds__(256) void cvt2_f32_bf16(
    const float* __restrict__ s0, unsigned short* __restrict__ d0, int n0,
    const float* __restrict__ s1, unsigned short* __restrict__ d1, int n1)
{
  int i = blockIdx.x * 256 + threadIdx.x;
  const float* src; unsigned short* dst;
  if (i < n0) { src = s0; dst = d0; }
  else        { i -= n0; if (i >= n1) return; src = s1; dst = d1; }
  f32x4 v = *reinterpret_cast<const f32x4*>(src + (size_t)i * 4);
  ushort4 o;
  o.x = f2bf(v[0]); o.y = f2bf(v[1]); o.z = f2bf(v[2]); o.w = f2bf(v[3]);
  *reinterpret_cast<ushort4*>(dst + (size_t)i * 4) = o;
}

// ---------------------------------------------------------------------------
// 256xNT-tile 8-phase GEMM: C[M,N] = A[M,K] * B[N,K]^T, K=4096 fixed.
// (unchanged: GEMM1 1034 TF, 0 bank conflicts)
// ---------------------------------------------------------------------------
template <typename OutT, int NT>
__global__ __launch_bounds__(512, 2) void gemm256(
    const unsigned short* __restrict__ A,
    const unsigned short* __restrict__ Bw,
    OutT* __restrict__ C, int M, int N)
{
  constexpr int K  = 4096;
  constexpr int NI = (K / 64) / 2;     // 32 iterations, 2 K-tiles each
  constexpr int NB = NT / 64;          // B chunks per tile (3 or 4)
  constexpr int NN = NT / 64;          // n-frags per wave
  constexpr int WN = NT / 4;           // per-wave N extent
  constexpr int BBUF = NT * 128;       // B bytes per buffer
  __shared__ __align__(16) char lds[65536 + 2 * BBUF];

  const int tid  = threadIdx.x;
  const int lane = tid & 63;
  const int wave = tid >> 6;
  const int wr = wave >> 2;            // 0..1  (M half)
  const int wc = wave & 3;             // 0..3  (N quarter)
  const int lr = lane & 15;
  const int lk = (lane >> 4) * 8;

  int id  = blockIdx.y * gridDim.x + blockIdx.x;
  const int nwg = gridDim.x * gridDim.y;
  if ((nwg & 7) == 0) { const int q = nwg >> 3; id = (id & 7) * q + (id >> 3); }
  const int row0 = (id / gridDim.x) * 256;
  const int col0 = (id % gridDim.x) * NT;

  // A staging: 2 halves x 2 loads/thread (16KB each).
  int rwA[2], csA[2], dbA[2];
#pragma unroll
  for (int j = 0; j < 2; ++j) {
    dbA[j] = j * 8192 + tid * 16;
    rwA[j] = dbA[j] >> 7;
    csA[j] = ((dbA[j] & 127) ^ ((rwA[j] & 7) << 4)) >> 1;
  }
  auto stA = [&](int buf, int h, int t) {
#pragma unroll
    for (int j = 0; j < 2; ++j)
      cp16(A + (size_t)(row0 + h * 128 + rwA[j]) * K + t * 64 + csA[j],
           lds + buf * 32768 + h * 16384 + dbA[j]);
  };
  // B staging: NB chunks x 1 load/thread (8KB each, 64 rows).
  const int dbB = tid * 16;
  const int rwB = dbB >> 7;                              // 0..63
  const int csB = ((dbB & 127) ^ ((rwB & 7) << 4)) >> 1; // chunk row base %8==0
  auto stB = [&](int buf, int c, int t) {
    cp16(Bw + (size_t)(col0 + c * 64 + rwB) * K + t * 64 + csB,
         lds + 65536 + buf * BBUF + c * 8192 + dbB);
  };

  const int cb0 = ((0 + lk) << 1) ^ ((lr & 7) << 4);
  const int cb1 = ((32 + lk) << 1) ^ ((lr & 7) << 4);
  const int aRowB = (wr * 128 + lr) * 128;
  const int bRowB = (wc * WN + lr) * 128;

  f32x4 acc[8][NN];
#pragma unroll
  for (int m = 0; m < 8; ++m)
#pragma unroll
    for (int n = 0; n < NN; ++n) acc[m][n] = (f32x4){0.f, 0.f, 0.f, 0.f};
  bf16x8 bfr[NN][2];

#define FENCE asm volatile("" ::: "memory")
#define VMNB  do { if constexpr (NB == 4) asm volatile("s_waitcnt vmcnt(4)" ::: "memory"); \
                   else                   asm volatile("s_waitcnt vmcnt(3)" ::: "memory"); } while (0)
#define VM0   asm volatile("s_waitcnt vmcnt(0)" ::: "memory")

#define PHASE(p, buf, STAGE, WAIT)                                             \
  {                                                                            \
    if ((p) == 0) {                                                            \
      _Pragma("unroll")                                                        \
      for (int n = 0; n < NN; ++n) {                                           \
        bfr[n][0] = ld8b(lds, 65536 + (buf) * BBUF + bRowB + n * 2048 + cb0);  \
        bfr[n][1] = ld8b(lds, 65536 + (buf) * BBUF + bRowB + n * 2048 + cb1);  \
      }                                                                        \
    }                                                                          \
    bf16x8 a00 = ld8b(lds, (buf) * 32768 + aRowB + ((p) * 2 + 0) * 2048 + cb0);\
    bf16x8 a01 = ld8b(lds, (buf) * 32768 + aRowB + ((p) * 2 + 0) * 2048 + cb1);\
    bf16x8 a10 = ld8b(lds, (buf) * 32768 + aRowB + ((p) * 2 + 1) * 2048 + cb0);\
    bf16x8 a11 = ld8b(lds, (buf) * 32768 + aRowB + ((p) * 2 + 1) * 2048 + cb1);\
    STAGE;                                                                     \
    FENCE;                                                                     \
    __builtin_amdgcn_s_barrier();                                              \
    __builtin_amdgcn_s_setprio(1);                                             \
    _Pragma("unroll")                                                          \
    for (int n = 0; n < NN; ++n) {                                             \
      acc[(p)*2+0][n] = __builtin_amdgcn_mfma_f32_16x16x32_bf16(a00, bfr[n][0], acc[(p)*2+0][n], 0, 0, 0); \
      acc[(p)*2+0][n] = __builtin_amdgcn_mfma_f32_16x16x32_bf16(a01, bfr[n][1], acc[(p)*2+0][n], 0, 0, 0); \
      acc[(p)*2+1][n] = __builtin_amdgcn_mfma_f32_16x16x32_bf16(a10, bfr[n][0], acc[(p)*2+1][n], 0, 0, 0); \
      acc[(p)*2+1][n] = __builtin_amdgcn_mfma_f32_16x16x32_bf16(a11, bfr[n][1], acc[(p)*2+1][n], 0, 0, 0); \
    }                                                                          \
    __builtin_amdgcn_s_setprio(0);                                             \
    WAIT;                                                                      \
    FENCE;                                                                     \
    __builtin_amdgcn_s_barrier();                                              \
  }

  // Prologue: tile0 B+A into buf0, tile1 B into buf1; allow tile1-B in flight.
#pragma unroll
  for (int c = 0; c < NB; ++c) stB(0, c, 0);
  stA(0, 0, 0); stA(0, 1, 0);
#pragma unroll
  for (int c = 0; c < NB; ++c) stB(1, c, 1);
  VMNB;
  FENCE;
  __builtin_amdgcn_s_barrier();

  for (int i = 0; i < NI; ++i) {
    const int t1  = 2 * i + 1;
    const int tn0 = 2 * i + 2;
    const int tn1 = 2 * i + 3;
    const bool pre = (i + 1 < NI);
    // K-tile 2i in buf0
    PHASE(0, 0, { stA(1, 0, t1); }, {});
    PHASE(1, 0, { stA(1, 1, t1); }, {});
    PHASE(2, 0, { if (pre) { stB(0, 0, tn0); stB(0, 1, tn0); } }, {});
    PHASE(3, 0, { if (pre) { _Pragma("unroll") for (int c = 2; c < NB; ++c) stB(0, c, tn0); } },
          { if (pre) { VMNB; } else { VM0; } });
    // K-tile 2i+1 in buf1
    PHASE(0, 1, { if (pre) stA(0, 0, tn0); }, {});
    PHASE(1, 1, { if (pre) stA(0, 1, tn0); }, {});
    PHASE(2, 1, { if (pre) { stB(1, 0, tn1); stB(1, 1, tn1); } }, {});
    PHASE(3, 1, { if (pre) { _Pragma("unroll") for (int c = 2; c < NB; ++c) stB(1, c, tn1); } },
          { if (pre) { VMNB; } });
  }
#undef PHASE
#undef FENCE
#undef VMNB
#undef VM0

  const int orow = (lane >> 4) * 4;
#pragma unroll
  for (int m = 0; m < 8; ++m) {
    const int gr0 = row0 + wr * 128 + m * 16 + orow;
#pragma unroll
    for (int n = 0; n < NN; ++n) {
      const int gc = col0 + wc * WN + n * 16 + lr;
#pragma unroll
      for (int r = 0; r < 4; ++r) {
        float val = acc[m][n][r];
        if constexpr (sizeof(OutT) == 2)
          C[(size_t)(gr0 + r) * N + gc] = f2bf(val);
        else
          C[(size_t)(gr0 + r) * N + gc] = val;
      }
    }
  }
}

// ---------------------------------------------------------------------------
// Split fused[B,S,48,128] into Qr (rope), Kr (rope), Vt (transposed).
// Vectorized (G13): 16B loads, 16B Q/K stores; V transposed stores scalar.
// ---------------------------------------------------------------------------
__global__ __launch_bounds__(256) void rope_scatter(
    const unsigned short* __restrict__ fused,
    unsigned short* __restrict__ Qr,
    unsigned short* __restrict__ Kr,
    unsigned short* __restrict__ Vt)
{
  int idx = blockIdx.x * 256 + threadIdx.x;  // [0, B*S*48*8)
  int dg = idx & 7;            // d = dg*8 + jj
  int t = idx >> 3;
  int e = t % 48;
  int bs = t / 48;
  int s = bs % S_;
  int b = bs / S_;
  int kvh = e / 6, j = e % 6;
  const unsigned short* src = fused + (size_t)bs * NE_ + e * 128 + dg * 8;
  u16x8 lo = *reinterpret_cast<const u16x8*>(src);
  u16x8 hi = *reinterpret_cast<const u16x8*>(src + 64);
  if (j == 5) {  // V: transposed store
    size_t base = (size_t)(b * KVH_ + kvh) * HD_ * S_ + s;
#pragma unroll
    for (int jj = 0; jj < 8; ++jj) {
      Vt[base + (size_t)(dg * 8 + jj) * S_]      = lo[jj];
      Vt[base + (size_t)(dg * 8 + jj + 64) * S_] = hi[jj];
    }
  } else {
    u16x8 olo, ohi;
#pragma unroll
    for (int jj = 0; jj < 8; ++jj) {
      int d = dg * 8 + jj;
      float x1 = bf2f(lo[jj]), x2 = bf2f(hi[jj]);
      float inv = __expf(-(float)d * (9.2103403719761836f / 64.0f));
      float ang = (float)s * inv;
      float sn, c;
      sincosf(ang, &sn, &c);
      olo[jj] = f2bf(x1 * c - x2 * sn);
      ohi[jj] = f2bf(x2 * c + x1 * sn);
    }
    unsigned short* dst;
    if (j == 4) dst = Kr + ((size_t)(b * KVH_ + kvh) * S_ + s) * HD_;
    else        dst = Qr + ((size_t)(b * H_ + kvh * 4 + j) * S_ + s) * HD_;
    *reinterpret_cast<u16x8*>(dst + dg * 8)      = olo;
    *reinterpret_cast<u16x8*>(dst + dg * 8 + 64) = ohi;
  }
}

// ---------------------------------------------------------------------------
// Causal GQA flash attention, QBLK=128 (2 m-frags/wave, kf/vf shared by 2
// MFMAs). LDS cut to 64 KB so 2 blocks/CU fit (round-11's 80 KB silently
// dropped residency to 1 block/CU -> occupancy 11.6%):
//   K single-buffer 16K, V double-buffer 32K, P 16K.
// Per iter: QK^T(K) -> barrier (K dead) -> stage K(kb+1)+V(kb+1,alt)
//           -> softmax/P -> PV(V[cur]) -> barrier (lands stages).
// Staging latency hides under softmax+PV. Log2 softmax, per-lane partials,
// defer-max kept from round 10.
// ---------------------------------------------------------------------------
__global__ __launch_bounds__(256) void attn_fwd(
    const unsigned short* __restrict__ Qr,
    const unsigned short* __restrict__ Kr,
    const unsigned short* __restrict__ Vt,
    unsigned short* __restrict__ O)
{
  __shared__ __align__(16) unsigned short Kld[64 * 128];
  __shared__ __align__(16) unsigned short Vld[2][128 * 64];
  __shared__ __align__(16) unsigned short Pld[4][32 * 64];

  const int tid  = threadIdx.x;
  const int lane = tid & 63;
  const int wave = tid >> 6;
  const int bx = blockIdx.x;   // 0..7
  const int h  = blockIdx.y;   // 0..31
  const int b  = blockIdx.z;   // 0..1
  const int kvh = h >> 2;
  const int lr = lane & 15;
  const int lk = (lane >> 4) * 8;
  const int orow = (lane >> 4) * 4;

  const float SC2 = 0.08838834764831845f * 1.4426950408889634f; // scale*log2e
  const unsigned short* Kb = Kr + (size_t)(b * KVH_ + kvh) * S_ * HD_;
  const unsigned short* Vb = Vt + (size_t)(b * KVH_ + kvh) * HD_ * S_;

  auto stageK = [&](int kb) {
#pragma unroll
    for (int i = 0; i < 4; ++i) {
      const int db = i * 4096 + tid * 16;
      const int row  = db >> 8;                      // 256 B/row
      const int colb = (db & 255) ^ ((row & 7) << 4);
      cp16(Kb + (size_t)(kb * 64 + row) * HD_ + (colb >> 1),
           (char*)&Kld[0] + i * 4096 + wave * 1024);
    }
  };
  auto stageV = [&](int buf, int kb) {
#pragma unroll
    for (int i = 0; i < 4; ++i) {
      const int db = i * 4096 + tid * 16;
      const int row  = db >> 7;                      // 128 B/row
      const int colb = (db & 127) ^ ((row & 7) << 4);
      cp16(Vb + (size_t)row * S_ + kb * 64 + (colb >> 1),
           (char*)&Vld[buf][0] + i * 4096 + wave * 1024);
    }
  };

  for (int half = 0; half < 2; ++half) {
    const int qt = half ? (15 - bx) : bx;   // 128-row q-tile, 0..15
    const int nkb = 2 * (qt + 1);           // 64-row KV tiles (causal)

    bf16x8 qf[2][4];
#pragma unroll
    for (int fr = 0; fr < 2; ++fr) {
      const unsigned short* qbase =
          Qr + ((size_t)(b * H_ + h) * S_ + qt * 128 + wave * 32 + fr * 16 + lr) * HD_;
#pragma unroll
      for (int t = 0; t < 4; ++t) {
        union { bf16x8 v; unsigned short s2[8]; } u;
        u.v = ld8(qbase + t * 32 + lk);
#pragma unroll
        for (int jj = 0; jj < 8; ++jj) u.s2[jj] = f2bf(bf2f(u.s2[jj]) * SC2);
        qf[fr][t] = u.v;
      }
    }

    f32x4 acc_o[2][8];
#pragma unroll
    for (int fr = 0; fr < 2; ++fr)
#pragma unroll
      for (int dt = 0; dt < 8; ++dt) acc_o[fr][dt] = (f32x4){0.f, 0.f, 0.f, 0.f};
    float mrow[2][4], lpart[2][4];
#pragma unroll
    for (int fr = 0; fr < 2; ++fr)
#pragma unroll
      for (int r = 0; r < 4; ++r) { mrow[fr][r] = -1e30f; lpart[fr][r] = 0.f; }

    stageK(0);
    stageV(0, 0);
    __syncthreads();

    for (int kb = 0; kb < nkb; ++kb) {
      const int cur = kb & 1;
      const char* Vc = (const char*)&Vld[cur][0];

      // S = Q K^T: each kf read feeds BOTH m-frags
      f32x4 accs[2][4];
#pragma unroll
      for (int fr = 0; fr < 2; ++fr)
#pragma unroll
        for (int kt = 0; kt < 4; ++kt) accs[fr][kt] = (f32x4){0.f, 0.f, 0.f, 0.f};
      __builtin_amdgcn_s_setprio(1);
#pragma unroll
      for (int t = 0; t < 4; ++t) {
#pragma unroll
        for (int kt = 0; kt < 4; ++kt) {
          const int krow = kt * 16 + lr;
          const int kbyte = ((krow << 8) + ((t * 32 + lk) << 1)) ^ ((krow & 7) << 4);
          bf16x8 kf = ld8b(Kld, kbyte);
          accs[0][kt] = __builtin_amdgcn_mfma_f32_16x16x32_bf16(qf[0][t], kf, accs[0][kt], 0, 0, 0);
          accs[1][kt] = __builtin_amdgcn_mfma_f32_16x16x32_bf16(qf[1][t], kf, accs[1][kt], 0, 0, 0);
        }
      }
      __builtin_amdgcn_s_setprio(0);

      __syncthreads();   // all waves done reading K -> safe to overwrite
      if (kb + 1 < nkb) { stageK(kb + 1); stageV(cur ^ 1, kb + 1); }

      if (kb >= 2 * qt) {  // diagonal region: last two KV tiles
        const int koff = (kb - 2 * qt) * 64;
#pragma unroll
        for (int fr = 0; fr < 2; ++fr)
#pragma unroll
          for (int r = 0; r < 4; ++r) {
            const int qg = wave * 32 + fr * 16 + orow + r;
#pragma unroll
            for (int kt = 0; kt < 4; ++kt)
              if (koff + kt * 16 + lr > qg) accs[fr][kt][r] = -1e30f;
          }
      }

      // in-lane kt-max; defer-check without cross-lane reduce
      float mx[2][4];
#pragma unroll
      for (int fr = 0; fr < 2; ++fr)
#pragma unroll
        for (int r = 0; r < 4; ++r)
          mx[fr][r] = fmaxf(fmaxf(accs[fr][0][r], accs[fr][1][r]),
                            fmaxf(accs[fr][2][r], accs[fr][3][r]));
      int ok = 1;
#pragma unroll
      for (int fr = 0; fr < 2; ++fr)
#pragma unroll
        for (int r = 0; r < 4; ++r) ok &= (mx[fr][r] <= mrow[fr][r] + 8.f);
      if (!__all(ok)) {   // rare: running max grew; full rescale
#pragma unroll
        for (int fr = 0; fr < 2; ++fr) {
          float corr[4];
#pragma unroll
          for (int r = 0; r < 4; ++r) {
            float m = mx[fr][r];
#pragma unroll
            for (int msk = 8; msk >= 1; msk >>= 1) m = fmaxf(m, __shfl_xor(m, msk, 64));
            float mnew = fmaxf(mrow[fr][r], m);
            corr[r] = exp2a(mrow[fr][r] - mnew);
            mrow[fr][r] = mnew;
            lpart[fr][r] *= corr[r];
          }
#pragma unroll
          for (int dt = 0; dt < 8; ++dt)
#pragma unroll
            for (int r = 0; r < 4; ++r) acc_o[fr][dt][r] *= corr[r];
        }
      }

      // p = exp2(s - m); per-lane partials; bf16 P store (swizzled)
#pragma unroll
      for (int fr = 0; fr < 2; ++fr)
#pragma unroll
        for (int r = 0; r < 4; ++r) {
          const int prow = fr * 16 + orow + r;
#pragma unroll
          for (int kt = 0; kt < 4; ++kt) {
            float p = exp2a(accs[fr][kt][r] - mrow[fr][r]);
            lpart[fr][r] += p;
            const int pbyte = ((prow << 7) + ((kt * 16 + lr) << 1)) ^ ((prow & 7) << 4);
            *(__bf16*)((char*)&Pld[wave][0] + pbyte) = (__bf16)p;
          }
        }

      asm volatile("" ::: "memory");  // Pld ushort-write vs bf16x8-read (TBAA)

      // O += P V: each vf read feeds BOTH m-frags
      __builtin_amdgcn_s_setprio(1);
#pragma unroll
      for (int kc = 0; kc < 2; ++kc) {
        bf16x8 pf[2];
#pragma unroll
        for (int fr = 0; fr < 2; ++fr) {
          const int pr = fr * 16 + lr;
          pf[fr] = ld8b(&Pld[wave][0],
                        ((pr << 7) + ((kc * 32 + lk) << 1)) ^ ((pr & 7) << 4));
        }
#pragma unroll
        for (int dt = 0; dt < 8; ++dt) {
          const int vrow = dt * 16 + lr;
          const int vbyte = ((vrow << 7) + ((kc * 32 + lk) << 1)) ^ ((vrow & 7) << 4);
          bf16x8 vf = ld8b(Vc, vbyte);
          acc_o[0][dt] = __builtin_amdgcn_mfma_f32_16x16x32_bf16(pf[0], vf, acc_o[0][dt], 0, 0, 0);
          acc_o[1][dt] = __builtin_amdgcn_mfma_f32_16x16x32_bf16(pf[1], vf, acc_o[1][dt], 0, 0, 0);
        }
      }
      __builtin_amdgcn_s_setprio(0);

      __syncthreads();  // lands K/V stages (vmcnt drain) for next iter
    }

    // one cross-lane sum reduce per row at the end
#pragma unroll
    for (int fr = 0; fr < 2; ++fr)
#pragma unroll
      for (int r = 0; r < 4; ++r) {
        float s = lpart[fr][r];
#pragma unroll
        for (int msk = 8; msk >= 1; msk >>= 1) s += __shfl_xor(s, msk, 64);
        float inv = 1.f / s;
        size_t rowoff =
            (size_t)(b * S_ + qt * 128 + wave * 32 + fr * 16 + orow + r) * (H_ * HD_) + h * HD_;
#pragma unroll
        for (int dt = 0; dt < 8; ++dt)
          O[rowoff + dt * 16 + lr] = f2bf(acc_o[fr][dt][r] * inv);
      }
  }
}

// Diagnostic: if ws_size is too small, fill fp32 output with sentinel 12345.
__global__ void fill_sentinel(float* __restrict__ O, int n) {
  int i = blockIdx.x * 256 + threadIdx.x;
  if (i < n) O[i] = 12345.0f;
}

// ---------------------------------------------------------------------------
extern "C" void kernel_launch(void* const* d_in, const int* in_sizes, int n_in,
                              void* d_out, int out_size, void* d_ws, size_t ws_size,
                              hipStream_t stream) {
  const float* hidden = (const float*)d_in[0]; // [B,S,D] fp32
  const float* wqkv   = (const float*)d_in[1]; // [6144,4096] fp32
  const float* wdense = (const float*)d_in[2]; // [4096,4096] fp32
  float* out = (float*)d_out;                  // [B,S,4096] fp32

  const size_t NEED = 134217728;
  if (ws_size < NEED) {
    fill_sentinel<<<dim3((out_size + 255) / 256), dim3(256), 0, stream>>>(out, out_size);
    return;
  }

  char* ws = (char*)d_ws;
  // Phase 1 layout
  unsigned short* Hb    = (unsigned short*)(ws);                 // 33,554,432 B
  unsigned short* Wqb   = (unsigned short*)(ws + 33554432);      // 50,331,648 B
  unsigned short* fused = (unsigned short*)(ws + 83886080);      // 50,331,648 B
  // Phase 2 layout (after GEMM1: Hb/Wqb dead; Wdb sequenced AFTER GEMM1!)
  unsigned short* Qr    = (unsigned short*)(ws);                 // 33,554,432 B
  unsigned short* Kr    = (unsigned short*)(ws + 33554432);      //  8,388,608 B
  unsigned short* Vt    = (unsigned short*)(ws + 41943040);      //  8,388,608 B
  unsigned short* Wdb   = (unsigned short*)(ws + 50331648);      // 33,554,432 B
  unsigned short* attn_out = (unsigned short*)(ws + 83886080);   // 33,554,432 B (over fused)

  const int nH4 = B_ * S_ * D_ / 4;   // 4,194,304
  const int nQ4 = NE_ * D_ / 4;       // 6,291,456
  const int nD4 = D_ * D_ / 4;        // 4,194,304

  cvt2_f32_bf16<<<dim3((nH4 + nQ4 + 255) / 256), dim3(256), 0, stream>>>(
      hidden, Hb, nH4, wqkv, Wqb, nQ4);

  gemm256<unsigned short, 192><<<dim3(NE_ / 192, (B_ * S_) / 256), dim3(512), 0, stream>>>(
      Hb, Wqb, fused, B_ * S_, NE_);

  cvt_f32_bf16<<<dim3(nD4 / 256), dim3(256), 0, stream>>>(wdense, Wdb, nD4);

  rope_scatter<<<dim3((B_ * S_ * 48 * 8) / 256), dim3(256), 0, stream>>>(
      fused, Qr, Kr, Vt);

  attn_fwd<<<dim3(8, H_, B_), dim3(256), 0, stream>>>(Qr, Kr, Vt, attn_out);

  gemm256<float, 256><<<dim3(D_ / 256, (B_ * S_) / 256), dim3(512), 0, stream>>>(
      attn_out, Wdb, out, B_ * S_, D_);
}

// Round 13
// 524.052 us; speedup vs baseline: 1.0355x; 1.0090x over previous
//
#include <hip/hip_runtime.h>

#define B_   2
#define S_   2048
#define D_   4096
#define H_   32
#define KVH_ 8
#define HD_  128
#define NE_  6144   // (KVH*2+H)*HD

using f32x4  = __attribute__((ext_vector_type(4))) float;
using bf16x8 = __attribute__((ext_vector_type(8))) __bf16;
using u16x8  = __attribute__((ext_vector_type(8))) unsigned short;

__device__ __forceinline__ unsigned short f2bf(float f) {
  union { float f; unsigned u; } v; v.f = f;
  unsigned r = v.u + 0x7FFFu + ((v.u >> 16) & 1u);
  return (unsigned short)(r >> 16);
}
__device__ __forceinline__ float bf2f(unsigned short h) {
  union { unsigned u; float f; } v; v.u = ((unsigned)h) << 16; return v.f;
}
__device__ __forceinline__ bf16x8 ld8(const unsigned short* p) {
  return *reinterpret_cast<const bf16x8*>(p);
}
__device__ __forceinline__ bf16x8 ld8b(const void* base, int byte_off) {
  return *reinterpret_cast<const bf16x8*>((const char*)base + byte_off);
}
__device__ __forceinline__ void cp16(const void* g, void* l) {
  __builtin_amdgcn_global_load_lds(
      (const __attribute__((address_space(1))) void*)g,
      (__attribute__((address_space(3))) void*)l, 16, 0, 0);
}
__device__ __forceinline__ float exp2a(float x) {   // 2^x via v_exp_f32
  float r; asm("v_exp_f32 %0, %1" : "=v"(r) : "v"(x)); return r;
}

// ---------------------------------------------------------------------------
// fp32 -> bf16 (RNE), 4 elems/thread. Single-segment.
// ---------------------------------------------------------------------------
__global__ __launch_bounds__(256) void cvt_f32_bf16(
    const float* __restrict__ in, unsigned short* __restrict__ out, int n4)
{
  int i = blockIdx.x * 256 + threadIdx.x;
  if (i >= n4) return;
  f32x4 v = *reinterpret_cast<const f32x4*>(in + (size_t)i * 4);
  ushort4 o;
  o.x = f2bf(v[0]); o.y = f2bf(v[1]); o.z = f2bf(v[2]); o.w = f2bf(v[3]);
  *reinterpret_cast<ushort4*>(out + (size_t)i * 4) = o;
}

// Two segments in one launch (dests must be disjoint!).
__global__ __launch_bounds__(256) void cvt2_f32_bf16(
    const float* __restrict__ s0, unsigned short* __restrict__ d0, int n0,
    const float* __restrict__ s1, unsigned short* __restrict__ d1, int n1)
{
  int i = blockIdx.x * 256 + threadIdx.x;
  const float* src; unsigned short* dst;
  if (i < n0) { src = s0; dst = d0; }
  else        { i -= n0; if (i >= n1) return; src = s1; dst = d1; }
  f32x4 v = *reinterpret_cast<const f32x4*>(src + (size_t)i * 4);
  ushort4 o;
  o.x = f2bf(v[0]); o.y = f2bf(v[1]); o.z = f2bf(v[2]); o.w = f2bf(v[3]);
  *reinterpret_cast<ushort4*>(dst + (size_t)i * 4) = o;
}

// ---------------------------------------------------------------------------
// 256xNT-tile 8-phase GEMM: C[M,N] = A[M,K] * B[N,K]^T, K=4096 fixed.
// (unchanged: GEMM1 1034 TF, 0 bank conflicts)
// ---------------------------------------------------------------------------
template <typename OutT, int NT>
__global__ __launch_bounds__(512, 2) void gemm256(
    const unsigned short* __restrict__ A,
    const unsigned short* __restrict__ Bw,
    OutT* __restrict__ C, int M, int N)
{
  constexpr int K  = 4096;
  constexpr int NI = (K / 64) / 2;     // 32 iterations, 2 K-tiles each
  constexpr int NB = NT / 64;          // B chunks per tile (3 or 4)
  constexpr int NN = NT / 64;          // n-frags per wave
  constexpr int WN = NT / 4;           // per-wave N extent
  constexpr int BBUF = NT * 128;       // B bytes per buffer
  __shared__ __align__(16) char lds[65536 + 2 * BBUF];

  const int tid  = threadIdx.x;
  const int lane = tid & 63;
  const int wave = tid >> 6;
  const int wr = wave >> 2;            // 0..1  (M half)
  const int wc = wave & 3;             // 0..3  (N quarter)
  const int lr = lane & 15;
  const int lk = (lane >> 4) * 8;

  int id  = blockIdx.y * gridDim.x + blockIdx.x;
  const int nwg = gridDim.x * gridDim.y;
  if ((nwg & 7) == 0) { const int q = nwg >> 3; id = (id & 7) * q + (id >> 3); }
  const int row0 = (id / gridDim.x) * 256;
  const int col0 = (id % gridDim.x) * NT;

  // A staging: 2 halves x 2 loads/thread (16KB each).
  int rwA[2], csA[2], dbA[2];
#pragma unroll
  for (int j = 0; j < 2; ++j) {
    dbA[j] = j * 8192 + tid * 16;
    rwA[j] = dbA[j] >> 7;
    csA[j] = ((dbA[j] & 127) ^ ((rwA[j] & 7) << 4)) >> 1;
  }
  auto stA = [&](int buf, int h, int t) {
#pragma unroll
    for (int j = 0; j < 2; ++j)
      cp16(A + (size_t)(row0 + h * 128 + rwA[j]) * K + t * 64 + csA[j],
           lds + buf * 32768 + h * 16384 + dbA[j]);
  };
  // B staging: NB chunks x 1 load/thread (8KB each, 64 rows).
  const int dbB = tid * 16;
  const int rwB = dbB >> 7;                              // 0..63
  const int csB = ((dbB & 127) ^ ((rwB & 7) << 4)) >> 1; // chunk row base %8==0
  auto stB = [&](int buf, int c, int t) {
    cp16(Bw + (size_t)(col0 + c * 64 + rwB) * K + t * 64 + csB,
         lds + 65536 + buf * BBUF + c * 8192 + dbB);
  };

  const int cb0 = ((0 + lk) << 1) ^ ((lr & 7) << 4);
  const int cb1 = ((32 + lk) << 1) ^ ((lr & 7) << 4);
  const int aRowB = (wr * 128 + lr) * 128;
  const int bRowB = (wc * WN + lr) * 128;

  f32x4 acc[8][NN];
#pragma unroll
  for (int m = 0; m < 8; ++m)
#pragma unroll
    for (int n = 0; n < NN; ++n) acc[m][n] = (f32x4){0.f, 0.f, 0.f, 0.f};
  bf16x8 bfr[NN][2];

#define FENCE asm volatile("" ::: "memory")
#define VMNB  do { if constexpr (NB == 4) asm volatile("s_waitcnt vmcnt(4)" ::: "memory"); \
                   else                   asm volatile("s_waitcnt vmcnt(3)" ::: "memory"); } while (0)
#define VM0   asm volatile("s_waitcnt vmcnt(0)" ::: "memory")

#define PHASE(p, buf, STAGE, WAIT)                                             \
  {                                                                            \
    if ((p) == 0) {                                                            \
      _Pragma("unroll")                                                        \
      for (int n = 0; n < NN; ++n) {                                           \
        bfr[n][0] = ld8b(lds, 65536 + (buf) * BBUF + bRowB + n * 2048 + cb0);  \
        bfr[n][1] = ld8b(lds, 65536 + (buf) * BBUF + bRowB + n * 2048 + cb1);  \
      }                                                                        \
    }                                                                          \
    bf16x8 a00 = ld8b(lds, (buf) * 32768 + aRowB + ((p) * 2 + 0) * 2048 + cb0);\
    bf16x8 a01 = ld8b(lds, (buf) * 32768 + aRowB + ((p) * 2 + 0) * 2048 + cb1);\
    bf16x8 a10 = ld8b(lds, (buf) * 32768 + aRowB + ((p) * 2 + 1) * 2048 + cb0);\
    bf16x8 a11 = ld8b(lds, (buf) * 32768 + aRowB + ((p) * 2 + 1) * 2048 + cb1);\
    STAGE;                                                                     \
    FENCE;                                                                     \
    __builtin_amdgcn_s_barrier();                                              \
    __builtin_amdgcn_s_setprio(1);                                             \
    _Pragma("unroll")                                                          \
    for (int n = 0; n < NN; ++n) {                                             \
      acc[(p)*2+0][n] = __builtin_amdgcn_mfma_f32_16x16x32_bf16(a00, bfr[n][0], acc[(p)*2+0][n], 0, 0, 0); \
      acc[(p)*2+0][n] = __builtin_amdgcn_mfma_f32_16x16x32_bf16(a01, bfr[n][1], acc[(p)*2+0][n], 0, 0, 0); \
      acc[(p)*2+1][n] = __builtin_amdgcn_mfma_f32_16x16x32_bf16(a10, bfr[n][0], acc[(p)*2+1][n], 0, 0, 0); \
      acc[(p)*2+1][n] = __builtin_amdgcn_mfma_f32_16x16x32_bf16(a11, bfr[n][1], acc[(p)*2+1][n], 0, 0, 0); \
    }                                                                          \
    __builtin_amdgcn_s_setprio(0);                                             \
    WAIT;                                                                      \
    FENCE;                                                                     \
    __builtin_amdgcn_s_barrier();                                              \
  }

  // Prologue: tile0 B+A into buf0, tile1 B into buf1; allow tile1-B in flight.
#pragma unroll
  for (int c = 0; c < NB; ++c) stB(0, c, 0);
  stA(0, 0, 0); stA(0, 1, 0);
#pragma unroll
  for (int c = 0; c < NB; ++c) stB(1, c, 1);
  VMNB;
  FENCE;
  __builtin_amdgcn_s_barrier();

  for (int i = 0; i < NI; ++i) {
    const int t1  = 2 * i + 1;
    const int tn0 = 2 * i + 2;
    const int tn1 = 2 * i + 3;
    const bool pre = (i + 1 < NI);
    // K-tile 2i in buf0
    PHASE(0, 0, { stA(1, 0, t1); }, {});
    PHASE(1, 0, { stA(1, 1, t1); }, {});
    PHASE(2, 0, { if (pre) { stB(0, 0, tn0); stB(0, 1, tn0); } }, {});
    PHASE(3, 0, { if (pre) { _Pragma("unroll") for (int c = 2; c < NB; ++c) stB(0, c, tn0); } },
          { if (pre) { VMNB; } else { VM0; } });
    // K-tile 2i+1 in buf1
    PHASE(0, 1, { if (pre) stA(0, 0, tn0); }, {});
    PHASE(1, 1, { if (pre) stA(0, 1, tn0); }, {});
    PHASE(2, 1, { if (pre) { stB(1, 0, tn1); stB(1, 1, tn1); } }, {});
    PHASE(3, 1, { if (pre) { _Pragma("unroll") for (int c = 2; c < NB; ++c) stB(1, c, tn1); } },
          { if (pre) { VMNB; } });
  }
#undef PHASE
#undef FENCE
#undef VMNB
#undef VM0

  const int orow = (lane >> 4) * 4;
#pragma unroll
  for (int m = 0; m < 8; ++m) {
    const int gr0 = row0 + wr * 128 + m * 16 + orow;
#pragma unroll
    for (int n = 0; n < NN; ++n) {
      const int gc = col0 + wc * WN + n * 16 + lr;
#pragma unroll
      for (int r = 0; r < 4; ++r) {
        float val = acc[m][n][r];
        if constexpr (sizeof(OutT) == 2)
          C[(size_t)(gr0 + r) * N + gc] = f2bf(val);
        else
          C[(size_t)(gr0 + r) * N + gc] = val;
      }
    }
  }
}

// ---------------------------------------------------------------------------
// Split fused[B,S,48,128] into Qr (rope), Kr (rope), Vt (transposed).
// Vectorized (G13): 16B loads, 16B Q/K stores; V transposed stores scalar.
// ---------------------------------------------------------------------------
__global__ __launch_bounds__(256) void rope_scatter(
    const unsigned short* __restrict__ fused,
    unsigned short* __restrict__ Qr,
    unsigned short* __restrict__ Kr,
    unsigned short* __restrict__ Vt)
{
  int idx = blockIdx.x * 256 + threadIdx.x;  // [0, B*S*48*8)
  int dg = idx & 7;            // d = dg*8 + jj
  int t = idx >> 3;
  int e = t % 48;
  int bs = t / 48;
  int s = bs % S_;
  int b = bs / S_;
  int kvh = e / 6, j = e % 6;
  const unsigned short* src = fused + (size_t)bs * NE_ + e * 128 + dg * 8;
  u16x8 lo = *reinterpret_cast<const u16x8*>(src);
  u16x8 hi = *reinterpret_cast<const u16x8*>(src + 64);
  if (j == 5) {  // V: transposed store
    size_t base = (size_t)(b * KVH_ + kvh) * HD_ * S_ + s;
#pragma unroll
    for (int jj = 0; jj < 8; ++jj) {
      Vt[base + (size_t)(dg * 8 + jj) * S_]      = lo[jj];
      Vt[base + (size_t)(dg * 8 + jj + 64) * S_] = hi[jj];
    }
  } else {
    u16x8 olo, ohi;
#pragma unroll
    for (int jj = 0; jj < 8; ++jj) {
      int d = dg * 8 + jj;
      float x1 = bf2f(lo[jj]), x2 = bf2f(hi[jj]);
      float inv = __expf(-(float)d * (9.2103403719761836f / 64.0f));
      float ang = (float)s * inv;
      float sn, c;
      sincosf(ang, &sn, &c);
      olo[jj] = f2bf(x1 * c - x2 * sn);
      ohi[jj] = f2bf(x2 * c + x1 * sn);
    }
    unsigned short* dst;
    if (j == 4) dst = Kr + ((size_t)(b * KVH_ + kvh) * S_ + s) * HD_;
    else        dst = Qr + ((size_t)(b * H_ + kvh * 4 + j) * S_ + s) * HD_;
    *reinterpret_cast<u16x8*>(dst + dg * 8)      = olo;
    *reinterpret_cast<u16x8*>(dst + dg * 8 + 64) = ohi;
  }
}

// ---------------------------------------------------------------------------
// Causal GQA flash attention — round-10 structure restored (best measured:
// ~183 µs, occupancy 22%, VGPR 116): QBLK=64 (4 waves x 16 q-rows), K/V
// double-buffered (72 KB -> 2 blocks/CU), prefetch-first, one barrier/iter.
// Log2-domain softmax (Q pre-scaled by scale*log2e), per-lane l partials
// (one reduce at end), defer-max (THR=8), diagonal-only causal mask.
// QBLK=128 variants (r11/r12) hit the 1-wave/SIMD register wall (~288 regs).
// ---------------------------------------------------------------------------
__global__ __launch_bounds__(256) void attn_fwd(
    const unsigned short* __restrict__ Qr,
    const unsigned short* __restrict__ Kr,
    const unsigned short* __restrict__ Vt,
    unsigned short* __restrict__ O)
{
  __shared__ __align__(16) unsigned short Kld[2][64 * 128];
  __shared__ __align__(16) unsigned short Vld[2][128 * 64];
  __shared__ __align__(16) unsigned short Pld[4][16 * 64];

  const int tid  = threadIdx.x;
  const int lane = tid & 63;
  const int wave = tid >> 6;
  const int bx = blockIdx.x;   // 0..15
  const int h  = blockIdx.y;   // 0..31
  const int b  = blockIdx.z;   // 0..1
  const int kvh = h >> 2;
  const int lr = lane & 15;
  const int lk = (lane >> 4) * 8;
  const int orow = (lane >> 4) * 4;

  const float SC2 = 0.08838834764831845f * 1.4426950408889634f; // scale*log2e
  const unsigned short* Kb = Kr + (size_t)(b * KVH_ + kvh) * S_ * HD_;
  const unsigned short* Vb = Vt + (size_t)(b * KVH_ + kvh) * HD_ * S_;

  auto stage = [&](int buf, int kb) {
#pragma unroll
    for (int i = 0; i < 4; ++i) {
      const int db = i * 4096 + tid * 16;
      {  // K: 256 B/row
        const int row  = db >> 8;
        const int colb = (db & 255) ^ ((row & 7) << 4);
        cp16(Kb + (size_t)(kb * 64 + row) * HD_ + (colb >> 1),
             (char*)&Kld[buf][0] + i * 4096 + wave * 1024);
      }
      {  // V: 128 B/row
        const int row  = db >> 7;
        const int colb = (db & 127) ^ ((row & 7) << 4);
        cp16(Vb + (size_t)row * S_ + kb * 64 + (colb >> 1),
             (char*)&Vld[buf][0] + i * 4096 + wave * 1024);
      }
    }
  };

  for (int half = 0; half < 2; ++half) {
    const int qb = half ? (S_ / 64 - 1 - bx) : bx;

    const unsigned short* qbase =
        Qr + ((size_t)(b * H_ + h) * S_ + qb * 64 + wave * 16 + lr) * HD_;
    bf16x8 qf[4];
#pragma unroll
    for (int t = 0; t < 4; ++t) {
      union { bf16x8 v; unsigned short s2[8]; } u;
      u.v = ld8(qbase + t * 32 + lk);
#pragma unroll
      for (int jj = 0; jj < 8; ++jj) u.s2[jj] = f2bf(bf2f(u.s2[jj]) * SC2);
      qf[t] = u.v;
    }

    f32x4 acc_o[8];
#pragma unroll
    for (int dt = 0; dt < 8; ++dt) acc_o[dt] = (f32x4){0.f, 0.f, 0.f, 0.f};
    float mrow[4], lpart[4];
#pragma unroll
    for (int r = 0; r < 4; ++r) { mrow[r] = -1e30f; lpart[r] = 0.f; }

    stage(0, 0);
    __syncthreads();

    for (int kb = 0; kb <= qb; ++kb) {
      const int cur = kb & 1;
      if (kb < qb) stage(cur ^ 1, kb + 1);   // prefetch next tile FIRST

      const char* Kc = (const char*)&Kld[cur][0];
      const char* Vc = (const char*)&Vld[cur][0];

      // S = (scale*log2e) * Q K^T  (scale folded into Q)
      f32x4 accs[4];
#pragma unroll
      for (int kt = 0; kt < 4; ++kt) accs[kt] = (f32x4){0.f, 0.f, 0.f, 0.f};
      __builtin_amdgcn_s_setprio(1);
#pragma unroll
      for (int t = 0; t < 4; ++t) {
#pragma unroll
        for (int kt = 0; kt < 4; ++kt) {
          const int krow = kt * 16 + lr;
          const int kbyte = ((krow << 8) + ((t * 32 + lk) << 1)) ^ ((krow & 7) << 4);
          bf16x8 kf = ld8b(Kc, kbyte);
          accs[kt] = __builtin_amdgcn_mfma_f32_16x16x32_bf16(qf[t], kf, accs[kt], 0, 0, 0);
        }
      }
      __builtin_amdgcn_s_setprio(0);

      if (kb == qb) {  // block-uniform: mask only in the diagonal tile
#pragma unroll
        for (int r = 0; r < 4; ++r) {
          const int qg = wave * 16 + orow + r;
#pragma unroll
          for (int kt = 0; kt < 4; ++kt)
            if (kt * 16 + lr > qg) accs[kt][r] = -1e30f;
        }
      }

      // in-lane kt-max; defer-check without cross-lane reduce
      float mx[4];
#pragma unroll
      for (int r = 0; r < 4; ++r)
        mx[r] = fmaxf(fmaxf(accs[0][r], accs[1][r]), fmaxf(accs[2][r], accs[3][r]));
      int ok = (mx[0] <= mrow[0] + 8.f) && (mx[1] <= mrow[1] + 8.f) &&
               (mx[2] <= mrow[2] + 8.f) && (mx[3] <= mrow[3] + 8.f);
      if (!__all(ok)) {   // rare: running max grew; full rescale
        float corr[4];
#pragma unroll
        for (int r = 0; r < 4; ++r) {
          float m = mx[r];
#pragma unroll
          for (int msk = 8; msk >= 1; msk >>= 1) m = fmaxf(m, __shfl_xor(m, msk, 64));
          float mnew = fmaxf(mrow[r], m);
          corr[r] = exp2a(mrow[r] - mnew);
          mrow[r] = mnew;
          lpart[r] *= corr[r];
        }
#pragma unroll
        for (int dt = 0; dt < 8; ++dt)
#pragma unroll
          for (int r = 0; r < 4; ++r) acc_o[dt][r] *= corr[r];
      }

      // p = exp2(s - m); accumulate per-lane partials; store bf16 P
#pragma unroll
      for (int r = 0; r < 4; ++r) {
        const int prow = orow + r;
#pragma unroll
        for (int kt = 0; kt < 4; ++kt) {
          float p = exp2a(accs[kt][r] - mrow[r]);
          lpart[r] += p;
          const int pbyte = ((prow << 7) + ((kt * 16 + lr) << 1)) ^ ((prow & 7) << 4);
          *(__bf16*)((char*)&Pld[wave][0] + pbyte) = (__bf16)p;
        }
      }

      asm volatile("" ::: "memory");  // Pld ushort-write vs bf16x8-read (TBAA)

      // O += P V
      __builtin_amdgcn_s_setprio(1);
#pragma unroll
      for (int kc = 0; kc < 2; ++kc) {
        const int pbyte = ((lr << 7) + ((kc * 32 + lk) << 1)) ^ ((lr & 7) << 4);
        bf16x8 pf = ld8b(&Pld[wave][0], pbyte);
#pragma unroll
        for (int dt = 0; dt < 8; ++dt) {
          const int vrow = dt * 16 + lr;
          const int vbyte = ((vrow << 7) + ((kc * 32 + lk) << 1)) ^ ((vrow & 7) << 4);
          bf16x8 vf = ld8b(Vc, vbyte);
          acc_o[dt] = __builtin_amdgcn_mfma_f32_16x16x32_bf16(pf, vf, acc_o[dt], 0, 0, 0);
        }
      }
      __builtin_amdgcn_s_setprio(0);

      __syncthreads();  // lands prefetch + separates buffer reuse
    }

    // one cross-lane sum reduce at the end (was per-iteration)
#pragma unroll
    for (int r = 0; r < 4; ++r) {
      float s = lpart[r];
#pragma unroll
      for (int msk = 8; msk >= 1; msk >>= 1) s += __shfl_xor(s, msk, 64);
      float inv = 1.f / s;
      size_t rowoff =
          (size_t)(b * S_ + qb * 64 + wave * 16 + orow + r) * (H_ * HD_) + h * HD_;
#pragma unroll
      for (int dt = 0; dt < 8; ++dt)
        O[rowoff + dt * 16 + lr] = f2bf(acc_o[dt][r] * inv);
    }
  }
}

// Diagnostic: if ws_size is too small, fill fp32 output with sentinel 12345.
__global__ void fill_sentinel(float* __restrict__ O, int n) {
  int i = blockIdx.x * 256 + threadIdx.x;
  if (i < n) O[i] = 12345.0f;
}

// ---------------------------------------------------------------------------
extern "C" void kernel_launch(void* const* d_in, const int* in_sizes, int n_in,
                              void* d_out, int out_size, void* d_ws, size_t ws_size,
                              hipStream_t stream) {
  const float* hidden = (const float*)d_in[0]; // [B,S,D] fp32
  const float* wqkv   = (const float*)d_in[1]; // [6144,4096] fp32
  const float* wdense = (const float*)d_in[2]; // [4096,4096] fp32
  float* out = (float*)d_out;                  // [B,S,4096] fp32

  const size_t NEED = 134217728;
  if (ws_size < NEED) {
    fill_sentinel<<<dim3((out_size + 255) / 256), dim3(256), 0, stream>>>(out, out_size);
    return;
  }

  char* ws = (char*)d_ws;
  // Phase 1 layout
  unsigned short* Hb    = (unsigned short*)(ws);                 // 33,554,432 B
  unsigned short* Wqb   = (unsigned short*)(ws + 33554432);      // 50,331,648 B
  unsigned short* fused = (unsigned short*)(ws + 83886080);      // 50,331,648 B
  // Phase 2 layout (after GEMM1: Hb/Wqb dead; Wdb sequenced AFTER GEMM1!)
  unsigned short* Qr    = (unsigned short*)(ws);                 // 33,554,432 B
  unsigned short* Kr    = (unsigned short*)(ws + 33554432);      //  8,388,608 B
  unsigned short* Vt    = (unsigned short*)(ws + 41943040);      //  8,388,608 B
  unsigned short* Wdb   = (unsigned short*)(ws + 50331648);      // 33,554,432 B
  unsigned short* attn_out = (unsigned short*)(ws + 83886080);   // 33,554,432 B (over fused)

  const int nH4 = B_ * S_ * D_ / 4;   // 4,194,304
  const int nQ4 = NE_ * D_ / 4;       // 6,291,456
  const int nD4 = D_ * D_ / 4;        // 4,194,304

  cvt2_f32_bf16<<<dim3((nH4 + nQ4 + 255) / 256), dim3(256), 0, stream>>>(
      hidden, Hb, nH4, wqkv, Wqb, nQ4);

  gemm256<unsigned short, 192><<<dim3(NE_ / 192, (B_ * S_) / 256), dim3(512), 0, stream>>>(
      Hb, Wqb, fused, B_ * S_, NE_);

  cvt_f32_bf16<<<dim3(nD4 / 256), dim3(256), 0, stream>>>(wdense, Wdb, nD4);

  rope_scatter<<<dim3((B_ * S_ * 48 * 8) / 256), dim3(256), 0, stream>>>(
      fused, Qr, Kr, Vt);

  attn_fwd<<<dim3(16, H_, B_), dim3(256), 0, stream>>>(Qr, Kr, Vt, attn_out);

  gemm256<float, 256><<<dim3(D_ / 256, (B_ * S_) / 256), dim3(512), 0, stream>>>(
      attn_out, Wdb, out, B_ * S_, D_);
}